// Round 1
// baseline (196.947 us; speedup 1.0000x reference)
//
#include <hip/hip_runtime.h>

// 3D trilinear warp (grid_sample, align_corners=True, border padding).
// image: (B=2, C=1, D=160, H=192, W=192) f32
// ddf:   (B=2, 3, D, H, W) f32, channels = (dz, dy, dx) in voxel units
// out:   (B, 1, D, H, W) f32
//
// Key simplification: normalized-coords roundtrip collapses to
//   ix = x + dx; iy = y + dy; iz = z + dz  (then clamp to borders).

constexpr int D_ = 160, H_ = 192, W_ = 192;
constexpr int HW_ = H_ * W_;
constexpr int N_ = D_ * HW_;       // per-batch voxel count = 5,898,240
constexpr int B_ = 2;
constexpr int TOTAL_ = B_ * N_;    // 11,796,480

__global__ __launch_bounds__(256) void warp3d_kernel(
    const float* __restrict__ img,   // (B,1,D,H,W)
    const float* __restrict__ ddf,   // (B,3,D,H,W)
    float* __restrict__ out)         // (B,1,D,H,W)
{
    int idx = blockIdx.x * 256 + threadIdx.x;
    if (idx >= TOTAL_) return;

    int b = idx / N_;
    int s = idx - b * N_;
    int z = s / HW_;
    int r = s - z * HW_;
    int y = r / W_;
    int x = r - y * W_;

    // ddf channel streams: contiguous per channel -> coalesced scalar loads
    const float* dd = ddf + (size_t)b * 3 * N_ + s;
    float dz = dd[0];
    float dy = dd[(size_t)N_];
    float dx = dd[(size_t)2 * N_];

    // warped coords, border-clamped
    float ix = fminf(fmaxf((float)x + dx, 0.0f), (float)(W_ - 1));
    float iy = fminf(fmaxf((float)y + dy, 0.0f), (float)(H_ - 1));
    float iz = fminf(fmaxf((float)z + dz, 0.0f), (float)(D_ - 1));

    float fx = floorf(ix), fy = floorf(iy), fz = floorf(iz);
    float wx = ix - fx, wy = iy - fy, wz = iz - fz;

    int x0 = (int)fx, y0 = (int)fy, z0 = (int)fz;
    int x1 = min(x0 + 1, W_ - 1);
    int y1 = min(y0 + 1, H_ - 1);
    int z1 = min(z0 + 1, D_ - 1);

    const float* im = img + (size_t)b * N_;

    int zo0 = z0 * HW_, zo1 = z1 * HW_;
    int yo0 = y0 * W_,  yo1 = y1 * W_;

    float v000 = im[zo0 + yo0 + x0];
    float v001 = im[zo0 + yo0 + x1];
    float v010 = im[zo0 + yo1 + x0];
    float v011 = im[zo0 + yo1 + x1];
    float v100 = im[zo1 + yo0 + x0];
    float v101 = im[zo1 + yo0 + x1];
    float v110 = im[zo1 + yo1 + x0];
    float v111 = im[zo1 + yo1 + x1];

    float c00 = v000 + (v001 - v000) * wx;
    float c01 = v010 + (v011 - v010) * wx;
    float c10 = v100 + (v101 - v100) * wx;
    float c11 = v110 + (v111 - v110) * wx;

    float c0 = c00 + (c01 - c00) * wy;
    float c1 = c10 + (c11 - c10) * wy;

    out[idx] = c0 + (c1 - c0) * wz;
}

extern "C" void kernel_launch(void* const* d_in, const int* in_sizes, int n_in,
                              void* d_out, int out_size, void* d_ws, size_t ws_size,
                              hipStream_t stream) {
    const float* img = (const float*)d_in[0];
    const float* ddf = (const float*)d_in[1];
    float* out = (float*)d_out;

    int blocks = (TOTAL_ + 255) / 256;
    warp3d_kernel<<<blocks, 256, 0, stream>>>(img, ddf, out);
}

// Round 3
// 193.170 us; speedup vs baseline: 1.0196x; 1.0196x over previous
//
#include <hip/hip_runtime.h>

// 3D trilinear warp (grid_sample, align_corners=True, border padding).
// image: (B=2, 1, 160, 192, 192) f32 | ddf: (B,3,D,H,W) f32 (dz,dy,dx voxels)
//
// Round-2 structure: 4 voxels per thread (along x).
//  - ddf read as 3x float4 (non-temporal), out written as float4 (non-temporal)
//  - per voxel, the 8 corner gathers become 4x 8-byte (float2) gathers using
//    x0 = min(floor(ix), W-2), wx = ix - x0  (border case folds into wx=1,
//    numerically identical to the reference's clamp of x1).

typedef float f32x4 __attribute__((ext_vector_type(4)));
typedef float f32x2 __attribute__((ext_vector_type(2)));

constexpr int D_ = 160, H_ = 192, W_ = 192;
constexpr int HW_ = H_ * W_;
constexpr int N_ = D_ * HW_;        // 5,898,240 per batch
constexpr int B_ = 2;
constexpr int TOTAL_ = B_ * N_;     // 11,796,480
constexpr int NG_ = N_ / 4;         // float4 groups per batch (1,474,560)
constexpr int GROUPS_ = TOTAL_ / 4; // 2,949,120  (= 11520 * 256 exactly)

__global__ __launch_bounds__(256) void warp3d_kernel(
    const float* __restrict__ img,    // (B,1,D,H,W)
    const f32x4* __restrict__ ddf4,   // (B,3,D,H,W) viewed as float4
    f32x4* __restrict__ out4)         // (B,1,D,H,W) viewed as float4
{
    int g = blockIdx.x * 256 + threadIdx.x;   // grid covers GROUPS_ exactly

    int b  = g / NG_;
    int s4 = g - b * NG_;
    int s  = s4 * 4;
    int z  = s / HW_;
    int r  = s - z * HW_;
    int y  = r / W_;
    int x  = r - y * W_;    // multiple of 4; x..x+3 stay in-row (W%4==0)

    const f32x4* dd = ddf4 + (size_t)b * 3 * NG_ + s4;
    f32x4 dzv = __builtin_nontemporal_load(dd);
    f32x4 dyv = __builtin_nontemporal_load(dd + NG_);
    f32x4 dxv = __builtin_nontemporal_load(dd + 2 * NG_);

    const float* im = img + (size_t)b * N_;

    float res[4];
    float fy = (float)y, fz = (float)z;

#pragma unroll
    for (int i = 0; i < 4; ++i) {
        float ix = fminf(fmaxf((float)(x + i) + dxv[i], 0.0f), (float)(W_ - 1));
        float iy = fminf(fmaxf(fy + dyv[i], 0.0f), (float)(H_ - 1));
        float iz = fminf(fmaxf(fz + dzv[i], 0.0f), (float)(D_ - 1));

        // coords >= 0, so int-cast == floor; clamp base so +1 stays in-bounds.
        int x0 = min((int)ix, W_ - 2);
        int y0 = min((int)iy, H_ - 2);
        int z0 = min((int)iz, D_ - 2);

        float wx = ix - (float)x0;   // in [0,1]; border -> 1.0 (same value as ref)
        float wy = iy - (float)y0;
        float wz = iz - (float)z0;

        const float* p = im + z0 * HW_ + y0 * W_ + x0;

        f32x2 v00 = *(const f32x2*)(p);             // (z0,y0,x0..x0+1)
        f32x2 v01 = *(const f32x2*)(p + W_);        // (z0,y1,..)
        f32x2 v10 = *(const f32x2*)(p + HW_);       // (z1,y0,..)
        f32x2 v11 = *(const f32x2*)(p + HW_ + W_);  // (z1,y1,..)

        float c00 = v00.x + (v00.y - v00.x) * wx;
        float c01 = v01.x + (v01.y - v01.x) * wx;
        float c10 = v10.x + (v10.y - v10.x) * wx;
        float c11 = v11.x + (v11.y - v11.x) * wx;

        float c0 = c00 + (c01 - c00) * wy;
        float c1 = c10 + (c11 - c10) * wy;

        res[i] = c0 + (c1 - c0) * wz;
    }

    f32x4 o = {res[0], res[1], res[2], res[3]};
    __builtin_nontemporal_store(o, out4 + g);
}

extern "C" void kernel_launch(void* const* d_in, const int* in_sizes, int n_in,
                              void* d_out, int out_size, void* d_ws, size_t ws_size,
                              hipStream_t stream) {
    const float* img  = (const float*)d_in[0];
    const f32x4* ddf4 = (const f32x4*)d_in[1];
    f32x4*       out4 = (f32x4*)d_out;

    int blocks = GROUPS_ / 256;   // 11520, exact
    warp3d_kernel<<<blocks, 256, 0, stream>>>(img, ddf4, out4);
}

// Round 4
// 165.885 us; speedup vs baseline: 1.1872x; 1.1645x over previous
//
#include <hip/hip_runtime.h>

// 3D trilinear warp (grid_sample, align_corners=True, border padding).
// image: (B=2, 1, 160, 192, 192) f32 | ddf: (B,3,D,H,W) f32 (dz,dy,dx voxels)
//
// Round-4 structure:
//  - 4 voxels/thread (float4 ddf read, float4 out write, non-temporal)
//  - batch: compute ALL 16 gather addresses, issue ALL 16 float2 gathers,
//    then blend (maximize memory-level parallelism per wave)
//  - batch index b derived from blockIdx only -> im/dd/out bases are
//    wave-uniform (SGPR) + 32-bit per-lane offsets (cheaper addressing)
//  - XCD-chunked block swizzle (11520 % 8 == 0, bijective): each XCD's L2
//    caches a distinct contiguous z-slab instead of 8 duplicate copies.

typedef float f32x4 __attribute__((ext_vector_type(4)));
typedef float f32x2 __attribute__((ext_vector_type(2)));

constexpr int D_ = 160, H_ = 192, W_ = 192;
constexpr int HW_ = H_ * W_;
constexpr int N_ = D_ * HW_;             // 5,898,240 per batch
constexpr int NG_ = N_ / 4;              // 1,474,560 float4 groups per batch
constexpr int BLOCKS_PER_BATCH = NG_ / 256;      // 5760 (exact)
constexpr int TOTAL_BLOCKS = 2 * BLOCKS_PER_BATCH; // 11520 (exact, %8==0)

__global__ __launch_bounds__(256) void warp3d_kernel(
    const float* __restrict__ img,    // (B,1,D,H,W)
    const f32x4* __restrict__ ddf4,   // (B,3,D,H,W) as float4
    f32x4* __restrict__ out4)         // (B,1,D,H,W) as float4
{
    // XCD-chunked swizzle: consecutive swizzled ids -> same XCD L2 slab
    constexpr int CPX = TOTAL_BLOCKS / 8;    // 1440
    int bid = blockIdx.x;
    int swz = (bid % 8) * CPX + bid / 8;

    int b   = swz / BLOCKS_PER_BATCH;              // scalar (blockIdx-only)
    int blk = swz - b * BLOCKS_PER_BATCH;          // scalar
    int s4  = blk * 256 + threadIdx.x;             // float4-group index in batch
    int s   = s4 * 4;
    int z   = s / HW_;
    int r   = s - z * HW_;
    int y   = r / W_;
    int x   = r - y * W_;   // multiple of 4; x..x+3 in-row (W%4==0)

    const f32x4* dd = ddf4 + (size_t)b * 3 * NG_;  // uniform base
    f32x4 dzv = __builtin_nontemporal_load(dd + s4);
    f32x4 dyv = __builtin_nontemporal_load(dd + NG_ + s4);
    f32x4 dxv = __builtin_nontemporal_load(dd + 2 * NG_ + s4);

    const float* im = img + (size_t)b * N_;        // uniform base

    int off0[4];                 // element offset of (z0,y0,x0) row pair
    float wx[4], wy[4], wz[4];
    float fy = (float)y, fz = (float)z;

#pragma unroll
    for (int i = 0; i < 4; ++i) {
        float ix = fminf(fmaxf((float)(x + i) + dxv[i], 0.0f), (float)(W_ - 1));
        float iy = fminf(fmaxf(fy + dyv[i], 0.0f), (float)(H_ - 1));
        float iz = fminf(fmaxf(fz + dzv[i], 0.0f), (float)(D_ - 1));

        int x0 = min((int)ix, W_ - 2);   // coords >= 0 so int-cast == floor
        int y0 = min((int)iy, H_ - 2);
        int z0 = min((int)iz, D_ - 2);

        wx[i] = ix - (float)x0;          // border folds to wx=1 (== ref)
        wy[i] = iy - (float)y0;
        wz[i] = iz - (float)z0;

        off0[i] = z0 * HW_ + y0 * W_ + x0;
    }

    // Issue all 16 gathers back-to-back (16 outstanding per thread).
    f32x2 v00[4], v01[4], v10[4], v11[4];
#pragma unroll
    for (int i = 0; i < 4; ++i) {
        const float* p = im + off0[i];
        v00[i] = *(const f32x2*)(p);               // (z0,y0)
        v01[i] = *(const f32x2*)(p + W_);          // (z0,y1) : +768B imm
        v10[i] = *(const f32x2*)(p + HW_);         // (z1,y0)
        v11[i] = *(const f32x2*)(p + HW_ + W_);    // (z1,y1)
    }

    float res[4];
#pragma unroll
    for (int i = 0; i < 4; ++i) {
        float c00 = v00[i].x + (v00[i].y - v00[i].x) * wx[i];
        float c01 = v01[i].x + (v01[i].y - v01[i].x) * wx[i];
        float c10 = v10[i].x + (v10[i].y - v10[i].x) * wx[i];
        float c11 = v11[i].x + (v11[i].y - v11[i].x) * wx[i];
        float c0 = c00 + (c01 - c00) * wy[i];
        float c1 = c10 + (c11 - c10) * wy[i];
        res[i] = c0 + (c1 - c0) * wz[i];
    }

    f32x4 o = {res[0], res[1], res[2], res[3]};
    __builtin_nontemporal_store(o, out4 + (size_t)b * NG_ + s4);
}

extern "C" void kernel_launch(void* const* d_in, const int* in_sizes, int n_in,
                              void* d_out, int out_size, void* d_ws, size_t ws_size,
                              hipStream_t stream) {
    const float* img  = (const float*)d_in[0];
    const f32x4* ddf4 = (const f32x4*)d_in[1];
    f32x4*       out4 = (f32x4*)d_out;

    warp3d_kernel<<<TOTAL_BLOCKS, 256, 0, stream>>>(img, ddf4, out4);
}

// Round 5
// 120.177 us; speedup vs baseline: 1.6388x; 1.3803x over previous
//
#include <hip/hip_runtime.h>

// 3D trilinear warp (grid_sample, align_corners=True, border padding).
// image: (B=2, 1, 160, 192, 192) f32 | ddf: (B,3,D,H,W) f32 (dz,dy,dx voxels)
//
// Round-5: identical inner code to R4; ONLY the block->voxel mapping changes.
//  - 3D-tiled blocks: each 256-thread block covers a 32(x) x 8(y) x 4(z) tile
//    (4 voxels/thread along x). Gather footprint/block: ~80KB (vs 177KB for
//    the linear mapping) and ALL ~32 touches of an image cache line happen
//    within one block's lifetime -> L1 hits / MSHR merges instead of L2
//    round-trips. The TCP line-request path was the R4 limiter.
//  - XCD-chunked bijective swizzle kept (11520 % 8 == 0); tx fastest so
//    temporally-adjacent blocks on an XCD share halo lines in L2.

typedef float f32x4 __attribute__((ext_vector_type(4)));
typedef float f32x2 __attribute__((ext_vector_type(2)));

constexpr int D_ = 160, H_ = 192, W_ = 192;
constexpr int HW_ = H_ * W_;
constexpr int N_ = D_ * HW_;             // 5,898,240 per batch
constexpr int NG_ = N_ / 4;              // float4 groups per batch
constexpr int XT_ = W_ / 32;             // 6  x-tiles
constexpr int YT_ = H_ / 8;              // 24 y-tiles
constexpr int ZT_ = D_ / 4;              // 40 z-tiles
constexpr int TPB_ = XT_ * YT_ * ZT_;    // 5760 tiles per batch
constexpr int TOTAL_BLOCKS = 2 * TPB_;   // 11520 (%8 == 0)

__global__ __launch_bounds__(256) void warp3d_kernel(
    const float* __restrict__ img,    // (B,1,D,H,W)
    const f32x4* __restrict__ ddf4,   // (B,3,D,H,W) as float4
    f32x4* __restrict__ out4)         // (B,1,D,H,W) as float4
{
    // XCD-chunked bijective swizzle
    constexpr int CPX = TOTAL_BLOCKS / 8;    // 1440
    int bid = blockIdx.x;
    int swz = (bid % 8) * CPX + bid / 8;

    int b  = swz / TPB_;
    int t  = swz - b * TPB_;
    int tz = t / (XT_ * YT_);
    int r  = t - tz * (XT_ * YT_);
    int ty = r / XT_;
    int tx = r - ty * XT_;

    int sub = threadIdx.x & 63;
    int w   = threadIdx.x >> 6;          // z-slice within tile (0..3)
    int xg  = sub & 7;
    int yy  = sub >> 3;

    int x = tx * 32 + xg * 4;            // multiple of 4
    int y = ty * 8 + yy;
    int z = tz * 4 + w;
    int s  = (z * H_ + y) * W_ + x;
    int s4 = s >> 2;

    const f32x4* dd = ddf4 + (size_t)b * 3 * NG_;  // uniform base
    f32x4 dzv = __builtin_nontemporal_load(dd + s4);
    f32x4 dyv = __builtin_nontemporal_load(dd + NG_ + s4);
    f32x4 dxv = __builtin_nontemporal_load(dd + 2 * NG_ + s4);

    const float* im = img + (size_t)b * N_;        // uniform base

    int off0[4];
    float wx[4], wy[4], wz[4];
    float fy = (float)y, fz = (float)z;

#pragma unroll
    for (int i = 0; i < 4; ++i) {
        float ix = fminf(fmaxf((float)(x + i) + dxv[i], 0.0f), (float)(W_ - 1));
        float iy = fminf(fmaxf(fy + dyv[i], 0.0f), (float)(H_ - 1));
        float iz = fminf(fmaxf(fz + dzv[i], 0.0f), (float)(D_ - 1));

        int x0 = min((int)ix, W_ - 2);   // coords >= 0 so int-cast == floor
        int y0 = min((int)iy, H_ - 2);
        int z0 = min((int)iz, D_ - 2);

        wx[i] = ix - (float)x0;          // border folds to wx=1 (== ref)
        wy[i] = iy - (float)y0;
        wz[i] = iz - (float)z0;

        off0[i] = z0 * HW_ + y0 * W_ + x0;
    }

    // Issue all 16 gathers back-to-back (max MLP per wave).
    f32x2 v00[4], v01[4], v10[4], v11[4];
#pragma unroll
    for (int i = 0; i < 4; ++i) {
        const float* p = im + off0[i];
        v00[i] = *(const f32x2*)(p);               // (z0,y0)
        v01[i] = *(const f32x2*)(p + W_);          // (z0,y1)
        v10[i] = *(const f32x2*)(p + HW_);         // (z1,y0)
        v11[i] = *(const f32x2*)(p + HW_ + W_);    // (z1,y1)
    }

    float res[4];
#pragma unroll
    for (int i = 0; i < 4; ++i) {
        float c00 = v00[i].x + (v00[i].y - v00[i].x) * wx[i];
        float c01 = v01[i].x + (v01[i].y - v01[i].x) * wx[i];
        float c10 = v10[i].x + (v10[i].y - v10[i].x) * wx[i];
        float c11 = v11[i].x + (v11[i].y - v11[i].x) * wx[i];
        float c0 = c00 + (c01 - c00) * wy[i];
        float c1 = c10 + (c11 - c10) * wy[i];
        res[i] = c0 + (c1 - c0) * wz[i];
    }

    f32x4 o = {res[0], res[1], res[2], res[3]};
    __builtin_nontemporal_store(o, out4 + (size_t)b * NG_ + s4);
}

extern "C" void kernel_launch(void* const* d_in, const int* in_sizes, int n_in,
                              void* d_out, int out_size, void* d_ws, size_t ws_size,
                              hipStream_t stream) {
    const float* img  = (const float*)d_in[0];
    const f32x4* ddf4 = (const f32x4*)d_in[1];
    f32x4*       out4 = (f32x4*)d_out;

    warp3d_kernel<<<TOTAL_BLOCKS, 256, 0, stream>>>(img, ddf4, out4);
}